// Round 7
// baseline (244.925 us; speedup 1.0000x reference)
//
#include <hip/hip_runtime.h>
#include <stdint.h>

#define NPIX   65536
#define NIMG   8
#define NCH    64
#define KSEL   2048
#define NFG    1024
#define NRING  768
#define NBG    256
#define INV_TEMP 14.285714285714286f   // 1/0.07

typedef __attribute__((ext_vector_type(8))) short bf16x8;
typedef __attribute__((ext_vector_type(4))) float f32x4;

// ---------------- Threefry-2x32 (20 rounds), exactly as JAX's lowering ------
__device__ __forceinline__ void tf2x32(uint32_t k0, uint32_t k1,
                                       uint32_t& x0, uint32_t& x1) {
  const uint32_t ks2 = k0 ^ k1 ^ 0x1BD11BDAu;
  x0 += k0; x1 += k1;
#define TF_RND(r) { x0 += x1; x1 = (x1 << (r)) | (x1 >> (32 - (r))); x1 ^= x0; }
  TF_RND(13) TF_RND(15) TF_RND(26) TF_RND(6)
  x0 += k1;  x1 += ks2 + 1u;
  TF_RND(17) TF_RND(29) TF_RND(16) TF_RND(24)
  x0 += ks2; x1 += k0 + 2u;
  TF_RND(13) TF_RND(15) TF_RND(26) TF_RND(6)
  x0 += k0;  x1 += k1 + 3u;
  TF_RND(17) TF_RND(29) TF_RND(16) TF_RND(24)
  x0 += k1;  x1 += ks2 + 4u;
  TF_RND(13) TF_RND(15) TF_RND(26) TF_RND(6)
  x0 += ks2; x1 += k0 + 5u;
#undef TF_RND
}

// compute this image's 3 subkeys (JAX partitionable split of key(1))
__device__ __forceinline__ void img_keys(int img, uint32_t* k6) {
  uint32_t kb0 = 0u, kb1 = (uint32_t)img;
  tf2x32(0u, 1u, kb0, kb1);
  #pragma unroll
  for (int g = 0; g < 3; ++g) {
    uint32_t x0 = 0u, x1 = (uint32_t)g;
    tf2x32(kb0, kb1, x0, x1);
    k6[g * 2] = x0; k6[g * 2 + 1] = x1;
  }
}

// float -> bf16 round-to-nearest-even
__device__ __forceinline__ ushort f2bf(float f) {
  uint32_t u = __float_as_uint(f);
  return (ushort)((u + 0x7FFFu + ((u >> 16) & 1u)) >> 16);
}

// ---------------- kernel A: dilate + hash + histogram (fused) ---------------
// 32 blocks = 8 images x 4 row-bands of 64 rows (+10 halo). fg packed to
// u64 words via ballot; h-dilate shifts; v-dilate word-ORs. Then hash the
// band's 16384 pixels with their group's key into a 768-bin LDS histogram,
// written as per-block PARTIALS (plain stores -> no zero-ordering hazard).
// Block 0 also zeroes cnt/candcnt (64 u32) and out.
__global__ __launch_bounds__(1024) void dilate_hash_hist(
    const int* __restrict__ labels, uint64_t* __restrict__ fgw,
    uint64_t* __restrict__ dilw, uint32_t* __restrict__ histpart,
    uint32_t* __restrict__ zsmall, float* __restrict__ out) {
  __shared__ uint64_t fgs[336], hds[336], dls[256];   // 84 rows x 4 words
  __shared__ uint32_t lh[768];
  __shared__ uint32_t sk[6];
  const int tid = threadIdx.x;
  const int img = blockIdx.x >> 2;
  const int r0 = (blockIdx.x & 3) * 64;

  if (blockIdx.x == 0) {
    if (tid < 64) zsmall[tid] = 0u;          // cnt[24]+pad, candcnt[24]+pad
    if (tid == 0) out[0] = 0.0f;
  }
  if (tid == 0) img_keys(img, (uint32_t*)sk);
  for (int t = tid; t < 768; t += 1024) lh[t] = 0;

  // pack fg bits for rows [r0-10, r0+74) (out-of-range rows contribute 0)
  #pragma unroll
  for (int it = 0; it < 21; ++it) {
    int li = it * 1024 + tid;                // 0 .. 21503 (84*256)
    int hr = r0 - 10 + (li >> 8);
    int col = li & 255;
    bool bit = false;
    if (hr >= 0 && hr < 256) bit = (labels[(img << 16) + (hr << 8) + col] == 1);
    uint64_t m = __ballot(bit);
    if ((tid & 63) == 0) fgs[li >> 6] = m;
  }
  __syncthreads();

  // horizontal dilation radius 10 (4 words/row)
  for (int w = tid; w < 336; w += 1024) {
    int wc = w & 3;
    uint64_t x = fgs[w];
    uint64_t L = wc > 0 ? fgs[w - 1] : 0ull;
    uint64_t R = wc < 3 ? fgs[w + 1] : 0ull;
    uint64_t acc = x;
    #pragma unroll
    for (int s = 1; s <= 10; ++s) {
      acc |= (x << s) | (L >> (64 - s));
      acc |= (x >> s) | (R << (64 - s));
    }
    hds[w] = acc;
  }
  __syncthreads();

  // vertical dilation radius 10; stash dil words in LDS + write bitmaps
  if (tid < 256) {
    int r = tid >> 2, wc = tid & 3;
    uint64_t acc = 0ull;
    #pragma unroll
    for (int dr = 0; dr <= 20; ++dr) acc |= hds[(r + dr) * 4 + wc];
    dls[tid] = acc;
    fgw[img * 1024 + (r0 + r) * 4 + wc]  = fgs[(r + 10) * 4 + wc];
    dilw[img * 1024 + (r0 + r) * 4 + wc] = acc;
  }
  __syncthreads();

  // hash the band's 16384 pixels (each with its own group's key)
  const uint32_t K0a = sk[0], K0b = sk[1], K1a = sk[2], K1b = sk[3],
                 K2a = sk[4], K2b = sk[5];
  #pragma unroll
  for (int it = 0; it < 16; ++it) {
    int li = it * 1024 + tid;                // 0..16383: r = li>>8, col
    int r = li >> 8, col = li & 255;
    int wc = col >> 6, bp = col & 63;
    uint32_t fgbit = (uint32_t)((fgs[(r + 10) * 4 + wc] >> bp) & 1ull);
    uint32_t dilbit = (uint32_t)((dls[r * 4 + wc] >> bp) & 1ull);
    uint32_t grp = fgbit ? 0u : (dilbit ? 1u : 2u);
    uint32_t k0 = grp == 0 ? K0a : grp == 1 ? K1a : K2a;
    uint32_t k1 = grp == 0 ? K0b : grp == 1 ? K1b : K2b;
    uint32_t x0 = 0u, x1 = (uint32_t)(((r0 + r) << 8) | col);
    tf2x32(k0, k1, x0, x1);
    uint32_t m = (x0 ^ x1) >> 9;
    atomicAdd(&lh[grp * 256 + (m >> 15)], 1u);
  }
  __syncthreads();
  for (int t = tid; t < 768; t += 1024)
    histpart[blockIdx.x * 768 + t] = lh[t];
}

// ---------------- kernel B: thresholds + single-sweep emit ------------------
// 256 blocks (32/image). Sums the image's 4 hist partials, finds the
// threshold bucket per group, re-hashes its 2048 pixels into registers,
// then one count pass + one emit pass (register-resident, no global reread).
__global__ __launch_bounds__(256) void topk_emit(
    const uint64_t* __restrict__ fgw, const uint64_t* __restrict__ dilw,
    const uint32_t* __restrict__ histpart, uint32_t* __restrict__ TG,
    uint32_t* __restrict__ cnt, uint32_t* __restrict__ candcnt,
    unsigned long long* __restrict__ cand, int* __restrict__ idx_out) {
  __shared__ uint32_t hh[768];
  __shared__ uint64_t fgl[32], dll[32];
  __shared__ uint32_t sk[6];
  __shared__ uint32_t sT[3], loc[3], lbd[3], basA[3], basB[3];
  const int tid = threadIdx.x;
  const int b = blockIdx.x >> 5;
  const int base = blockIdx.x * 2048;
  const int w0 = (blockIdx.x & 31) * 32;

  for (int t = tid; t < 768; t += 256) {
    const uint32_t* hp = histpart + (b * 4) * 768 + t;
    hh[t] = hp[0] + hp[768] + hp[1536] + hp[2304];
  }
  if (tid == 0) img_keys(b, (uint32_t*)sk);
  if (tid < 32) fgl[tid] = fgw[b * 1024 + w0 + tid];
  else if (tid < 64) dll[tid - 32] = dilw[b * 1024 + w0 + tid - 32];
  if (tid < 3) { loc[tid] = 0; lbd[tid] = 0; }
  __syncthreads();

  if (tid < 3) {
    uint32_t nsel = tid == 0 ? NFG : tid == 1 ? NRING : NBG;
    const uint32_t* h = hh + tid * 256;
    uint32_t cum = 0; int T = 255;
    for (; T > 0; --T) {
      uint32_t c = h[T];
      if (cum + c >= nsel) break;
      cum += c;
    }
    sT[tid] = (uint32_t)T;
    if ((blockIdx.x & 31) == 0) {
      TG[(b * 3 + tid) * 2] = (uint32_t)T;
      TG[(b * 3 + tid) * 2 + 1] = cum;      // count strictly above bucket T
    }
  }
  __syncthreads();

  // hash once into registers; count pass
  uint32_t mv[8]; uint32_t gv[8];
  const uint32_t K0a = sk[0], K0b = sk[1], K1a = sk[2], K1b = sk[3],
                 K2a = sk[4], K2b = sk[5];
  #pragma unroll
  for (int k = 0; k < 8; ++k) {
    int off = k * 256 + tid;                  // 0..2047 within block
    int lw = off >> 6, bp = off & 63;
    uint32_t fgbit = (uint32_t)((fgl[lw] >> bp) & 1ull);
    uint32_t dilbit = (uint32_t)((dll[lw] >> bp) & 1ull);
    uint32_t grp = fgbit ? 0u : (dilbit ? 1u : 2u);
    uint32_t k0 = grp == 0 ? K0a : grp == 1 ? K1a : K2a;
    uint32_t k1 = grp == 0 ? K0b : grp == 1 ? K1b : K2b;
    uint32_t x0 = 0u, x1 = (uint32_t)((base + off) & 65535);
    tf2x32(k0, k1, x0, x1);
    uint32_t m = (x0 ^ x1) >> 9;
    mv[k] = m; gv[k] = grp;
    uint32_t T = sT[grp], bin = m >> 15;
    if (bin > T) atomicAdd(&loc[grp], 1u);
    else if (bin == T) atomicAdd(&lbd[grp], 1u);
  }
  __syncthreads();
  if (tid < 3) {
    basA[tid] = atomicAdd(&cnt[b * 3 + tid], loc[tid]);
    basB[tid] = atomicAdd(&candcnt[b * 3 + tid], lbd[tid]);
    loc[tid] = 0; lbd[tid] = 0;
  }
  __syncthreads();

  #pragma unroll
  for (int k = 0; k < 8; ++k) {
    uint32_t m = mv[k], g = gv[k];
    uint32_t T = sT[g], bin = m >> 15;
    int pix = (base + k * 256 + tid) & 65535;
    if (bin > T) {
      uint32_t o = atomicAdd(&loc[g], 1u);
      int seg = g == 0 ? 0 : g == 1 ? NFG : (NFG + NRING);
      idx_out[b * KSEL + seg + (int)(basA[g] + o)] = pix;
    } else if (bin == T) {
      uint32_t o = atomicAdd(&lbd[g], 1u);
      uint32_t c = basB[g] + o;
      if (c < 1024u)
        cand[(b * 3 + g) * 1024 + c] = ((unsigned long long)m << 16) | (uint32_t)pix;
    }
  }
}

// ---------------- kernel C: gather + fused tie-break rank -> bf16 rows ------
// Output fs[img][j][64] row-major bf16 == MFMA A/B fragment-friendly layout.
#define GA 16
__global__ __launch_bounds__(256) void gather_rank_t(
    const float* __restrict__ feats, const int* __restrict__ idx,
    const uint32_t* __restrict__ TG, const uint32_t* __restrict__ candcnt,
    const unsigned long long* __restrict__ cand, ushort* __restrict__ fs) {
  __shared__ float tile[GA * 65];
  __shared__ float ssb[16 * GA];
  __shared__ float sscale[GA];
  __shared__ int lidx[GA];
  __shared__ unsigned long long cb[1024];
  const int tid = threadIdx.x;
  const int img = blockIdx.x >> 7;            // 128 blocks per image
  const int win = (blockIdx.x & 127) * GA;    // anchor window within image
  int seg, segoff, nsel;
  if (win < NFG)               { seg = 0; segoff = 0;            nsel = NFG; }
  else if (win < NFG + NRING)  { seg = 1; segoff = NFG;          nsel = NRING; }
  else                         { seg = 2; segoff = NFG + NRING;  nsel = NBG; }
  const int task = img * 3 + seg;
  const uint32_t G = TG[task * 2 + 1];
  const int poslo = win - segoff;

  if (tid < GA) {
    if ((uint32_t)(poslo + tid) < G)
      lidx[tid] = idx[img * KSEL + win + tid];
  }
  const bool needRank = (uint32_t)(poslo + GA) > G;   // block-uniform
  if (needRank) {
    const int c = (int)(candcnt[task] < 1024u ? candcnt[task] : 1024u);
    const int r = nsel - (int)G;
    for (int i = tid; i < c; i += 256) cb[i] = cand[task * 1024 + i];
    __syncthreads();
    for (int i = tid; i < c; i += 256) {
      unsigned long long me = cb[i];
      uint32_t mm = (uint32_t)(me >> 16), pi = (uint32_t)(me & 0xFFFFu);
      int rank = 0;
      for (int j = 0; j < c; ++j) {
        unsigned long long o = cb[j];
        uint32_t om = (uint32_t)(o >> 16), op = (uint32_t)(o & 0xFFFFu);
        if (om > mm || (om == mm && op < pi)) ++rank;
      }
      if (rank < r) {
        int slot = (int)G + rank - poslo;
        if (slot >= 0 && slot < GA) lidx[slot] = (int)pi;
      }
    }
  }
  __syncthreads();

  // gather: a = tid&15 anchor, q = tid>>4 handles channels q*4 .. q*4+3
  const int a = tid & 15, q = tid >> 4;
  const int pix = lidx[a];
  const float* fb = feats + ((size_t)img * NCH + q * 4) * NPIX + pix;
  float ss = 0.f;
  #pragma unroll
  for (int k = 0; k < 4; ++k) {
    float v = fb[(size_t)k * NPIX];
    tile[a * 65 + q * 4 + k] = v;
    ss += v * v;
  }
  ssb[q * GA + a] = ss;
  __syncthreads();
  if (q == 0) {
    float tot = 0.f;
    #pragma unroll
    for (int q2 = 0; q2 < 16; ++q2) tot += ssb[q2 * GA + a];
    sscale[a] = 1.0f / fmaxf(sqrtf(tot), 1e-12f);
  }
  __syncthreads();

  // write phase: thread (row = tid>>4, chunk = tid&15) -> contiguous ushort4
  const int row = tid >> 4, c4 = tid & 15;
  const float sc = sscale[row];
  ushort4 v4;
  v4.x = f2bf(tile[row * 65 + c4 * 4 + 0] * sc);
  v4.y = f2bf(tile[row * 65 + c4 * 4 + 1] * sc);
  v4.z = f2bf(tile[row * 65 + c4 * 4 + 2] * sc);
  v4.w = f2bf(tile[row * 65 + c4 * 4 + 3] * sc);
  ((ushort4*)(fs + ((size_t)img * KSEL + win + row) * NCH))[c4] = v4;
}

// ---------------- kernel D: MFMA loss ---------------------------------------
// 256 blocks = 8 images x 32 anchor-tiles. 4 waves = 2 row-tiles x 2
// col-halves; per wave 64 col tiles x 2 mfma_f32_16x16x32_bf16 (K=64).
__global__ __launch_bounds__(256) void loss_mfma(const ushort* __restrict__ fs,
                                                 float* __restrict__ out) {
  const int img = blockIdx.x & 7;             // XCD swizzle
  const int a0 = (blockIdx.x >> 3) * 32;
  const ushort* X = fs + (size_t)img * KSEL * NCH;
  const int tid = threadIdx.x;
  const int lane = tid & 63, wave = tid >> 6;
  const int quad = lane >> 4, col = lane & 15;
  const int rt = wave >> 1, colh = wave & 1;

  __shared__ float redD[2][2][16];
  __shared__ float redP[2][16];

  const int arow = a0 + rt * 16 + col;
  const bf16x8* Ap = (const bf16x8*)(X + (size_t)arow * NCH + quad * 8);
  const bf16x8 a_lo = Ap[0];
  const bf16x8 a_hi = Ap[4];                  // +32 channels

  float pD[4] = {0.f, 0.f, 0.f, 0.f};
  float pP[4] = {0.f, 0.f, 0.f, 0.f};
  const int ct0 = colh * 64;
  const int mbase = a0 + rt * 16 + quad * 4;  // D rows for this lane

  for (int ct = ct0; ct < ct0 + 64; ++ct) {
    const int j = ct * 16 + col;              // D column for this lane
    const bf16x8* Bp = (const bf16x8*)(X + (size_t)j * NCH + quad * 8);
    bf16x8 b_lo = Bp[0];
    bf16x8 b_hi = Bp[4];
    f32x4 d = {0.f, 0.f, 0.f, 0.f};
    d = __builtin_amdgcn_mfma_f32_16x16x32_bf16(a_lo, b_lo, d, 0, 0, 0);
    d = __builtin_amdgcn_mfma_f32_16x16x32_bf16(a_hi, b_hi, d, 0, 0, 0);
    #pragma unroll
    for (int r = 0; r < 4; ++r) {
      float e = __expf(d[r] * INV_TEMP);
      if (j == mbase + r) e = 0.f;            // ~eye (only hits in colh 0)
      pD[r] += e;
      if (colh == 0) pP[r] += e;              // fg columns = tiles 0..63
    }
  }

  #pragma unroll
  for (int o = 1; o < 16; o <<= 1) {
    #pragma unroll
    for (int r = 0; r < 4; ++r) {
      pD[r] += __shfl_xor(pD[r], o);
      pP[r] += __shfl_xor(pP[r], o);
    }
  }
  if (col == 0) {
    #pragma unroll
    for (int r = 0; r < 4; ++r) {
      redD[rt][colh][quad * 4 + r] = pD[r];
      if (colh == 0) redP[rt][quad * 4 + r] = pP[r];
    }
  }
  __syncthreads();

  float term = 0.f;
  if (tid < 32) {
    int lrt = tid >> 4, lr = tid & 15;
    float dsum = fmaxf(redD[lrt][0][lr] + redD[lrt][1][lr], 1e-8f);
    float psum = fmaxf(redP[lrt][lr], 1e-8f);
    term = __logf(dsum) - __logf(psum);
  }
  if (tid < 64) {
    #pragma unroll
    for (int o = 32; o > 0; o >>= 1) term += __shfl_xor(term, o);
    if (tid == 0) atomicAdd(out, term * (1.0f / (NFG * NIMG)));
  }
}

// ---------------- launcher ---------------------------------------------------
extern "C" void kernel_launch(void* const* d_in, const int* in_sizes, int n_in,
                              void* d_out, int out_size, void* d_ws, size_t ws_size,
                              hipStream_t stream) {
  const float* feats = (const float*)d_in[0];
  const int* labels  = (const int*)d_in[1];
  float* out = (float*)d_out;

  char* ws = (char*)d_ws;
  uint64_t* fgw      = (uint64_t*)(ws);                     // 64 KB [8][1024]
  uint64_t* dilw     = (uint64_t*)(ws + 65536);             // 64 KB
  uint32_t* histpart = (uint32_t*)(ws + 131072);            // 96 KB [32][768]
  uint32_t* TG       = (uint32_t*)(ws + 229376);            // 256 B
  uint32_t* cnt      = (uint32_t*)(ws + 229632);            // 128 B (24 used)
  uint32_t* candcnt  = (uint32_t*)(ws + 229760);            // 128 B (24 used)
  unsigned long long* cand = (unsigned long long*)(ws + 229888); // 192 KB
  int*      idx      = (int*)(ws + 426496);                 // 64 KB
  ushort*   fs       = (ushort*)(ws + 524288);              // 2 MB bf16

  hipLaunchKernelGGL(dilate_hash_hist, dim3(32), dim3(1024), 0, stream,
                     labels, fgw, dilw, histpart, cnt, out);
  hipLaunchKernelGGL(topk_emit, dim3(NIMG * 32), dim3(256), 0, stream,
                     fgw, dilw, histpart, TG, cnt, candcnt, cand, idx);
  hipLaunchKernelGGL(gather_rank_t, dim3((NIMG * KSEL) / GA), dim3(256), 0, stream,
                     feats, idx, TG, candcnt, cand, fs);
  hipLaunchKernelGGL(loss_mfma, dim3(NIMG * (NFG / 32)), dim3(256), 0, stream,
                     fs, out);
}